// Round 1
// 975.533 us; speedup vs baseline: 1.0106x; 1.0106x over previous
//
#include <hip/hip_runtime.h>
#include <hip/hip_bf16.h>
#include <stdint.h>

// ---- problem constants ----
#define VOCAB 32000
#define EMB   256
#define DEC   1024
#define ENC   1024
#define BB    128
#define SS    512
#define MTOT  (BB * SS)      // 65536
#define XCOLS (ENC + EMB)    // 1280
#define NG    (4 * DEC)      // 4096

typedef _Float16 half8  __attribute__((ext_vector_type(8)));
typedef _Float16 half4  __attribute__((ext_vector_type(4)));
typedef float    floatx4 __attribute__((ext_vector_type(4)));

__device__ __forceinline__ float fast_tanh(float x) {
    // tanh(x) = 1 - 2/(e^{2x}+1); exp2-based, safe at +-inf extremes
    float e = __builtin_amdgcn_exp2f(x * 2.885390082f); // e^(2x)
    return 1.0f - 2.0f * __builtin_amdgcn_rcpf(e + 1.0f);
}
__device__ __forceinline__ float fast_sigmoid(float x) {
    float e = __builtin_amdgcn_exp2f(-x * 1.442695041f); // e^(-x)
    return __builtin_amdgcn_rcpf(1.0f + e);
}

// async global->LDS, 16B per lane. LDS dest is wave-uniform base + lane*16.
__device__ __forceinline__ void gl_lds16(const void* g, void* l) {
    __builtin_amdgcn_global_load_lds(
        (const __attribute__((address_space(1))) uint32_t*)g,
        (__attribute__((address_space(3))) uint32_t*)l,
        16, 0, 0);
}

// ---- K0: W1 (K=ENC, N=DEC) fp32 -> w1t f16 [n][k] ----
__global__ void k_transpose_w1(const float* __restrict__ W1, _Float16* __restrict__ w1t) {
    __shared__ float tile[32][33];
    const int k0 = blockIdx.y * 32, n0 = blockIdx.x * 32;
    const int tx = threadIdx.x, ty = threadIdx.y; // (32,8)
    #pragma unroll
    for (int j = 0; j < 4; ++j)
        tile[ty + j * 8][tx] = W1[(size_t)(k0 + ty + j * 8) * DEC + n0 + tx];
    __syncthreads();
    #pragma unroll
    for (int j = 0; j < 4; ++j)
        w1t[(size_t)(n0 + ty + j * 8) * ENC + k0 + tx] = (_Float16)tile[tx][ty + j * 8];
}

// ---- K0b: enc fp32 -> f16 copy (rounding identical to the old in-kernel cvt) ----
__global__ void k_convert(const float* __restrict__ src, _Float16* __restrict__ dst) {
    const int stride = gridDim.x * blockDim.x;
    const int n8 = (MTOT * ENC) / 8;          // 8388608 half8 stores
    for (int i = blockIdx.x * blockDim.x + threadIdx.x; i < n8; i += stride) {
        floatx4 a = ((const floatx4*)src)[2 * i];
        floatx4 b = ((const floatx4*)src)[2 * i + 1];
        half8 h;
        #pragma unroll
        for (int e = 0; e < 4; ++e) { h[e] = (_Float16)a[e]; h[e + 4] = (_Float16)b[e]; }
        ((half8*)dst)[i] = h;
    }
}

// ---- K1: hp[b][n] = dh[b]@W2[:,n] + b2[n] + b1[n] ----
__global__ void k_hidden_proj(const float* __restrict__ dh, const float* __restrict__ W2,
                              const float* __restrict__ b1, const float* __restrict__ b2,
                              float* __restrict__ hp) {
    __shared__ float xs[8 * 1024];
    const int t = threadIdx.x;                 // 128
    const int n = blockIdx.x * 128 + t;        // 8 n-tiles
    const int b0 = blockIdx.y * 8;             // 16 b-tiles
    for (int i = t; i < 2048; i += 128)
        ((floatx4*)xs)[i] = ((const floatx4*)(dh + (size_t)b0 * 1024))[i];
    __syncthreads();
    float acc[8] = {0, 0, 0, 0, 0, 0, 0, 0};
    for (int k = 0; k < 1024; ++k) {
        float wval = W2[(size_t)k * 1024 + n];
        #pragma unroll
        for (int j = 0; j < 8; ++j) acc[j] += xs[j * 1024 + k] * wval;
    }
    const float bias = b1[n] + b2[n];
    #pragma unroll
    for (int j = 0; j < 8; ++j) hp[(size_t)(b0 + j) * 1024 + n] = acc[j] + bias;
}

// ---- K2 fast: score via m97-style f16 MFMA GEMM, global_load_lds staging,
//      XCD-grouped block mapping so all 8 n-blocks of an m-tile share one L2. ----
// grid 4096 linear: bits [2:0]=xcd, [5:3]=n-tile, [11:6]=m-tile-within-xcd.
__global__ __launch_bounds__(256) void k_score_f16(
    const _Float16* __restrict__ ench, const _Float16* __restrict__ w1t,
    const float* __restrict__ hp, const float* __restrict__ wv,
    float* __restrict__ scores)
{
    __shared__ _Float16 As[128 * 32];   // 8 KB, linear [row][k]
    __shared__ _Float16 Bs[128 * 32];   // 8 KB
    const int g   = blockIdx.x;
    const int xcd = g & 7;
    const int n0  = ((g >> 3) & 7) * 128;
    const int m0  = ((xcd << 6) + (g >> 6)) << 7;   // m-tile fully owned by one XCD
    const int b   = m0 >> 9;                        // batch row (512 m per batch)
    const int t = threadIdx.x;
    const int lane = t & 63, w = t >> 6;
    const int wm = (w >> 1) * 64, wn = (w & 1) * 64;
    const int col = lane & 15, q = lane >> 4;

    floatx4 acc[4][4];
    #pragma unroll
    for (int i = 0; i < 4; ++i)
        #pragma unroll
        for (int j = 0; j < 4; ++j) acc[i][j] = (floatx4){0.f, 0.f, 0.f, 0.f};

    // staging geometry: wave w owns rows [w*32, w*32+32). Each gl_lds16 writes
    // 1 KB = 16 rows; lane l -> row +(l>>2), f16 col (l&3)*8. Two passes each for A,B.
    const int srow = w * 32 + (lane >> 2);
    const int scol = (lane & 3) * 8;
    const _Float16* agp = ench + (size_t)(m0 + srow) * ENC + scol;
    const _Float16* bgp = w1t  + (size_t)(n0 + srow) * ENC + scol;
    _Float16* alp = &As[(w * 32) * 32];
    _Float16* blp = &Bs[(w * 32) * 32];

    for (int k0 = 0; k0 < ENC; k0 += 32) {
        __syncthreads();                       // prev-iter reads done before overwrite
        gl_lds16(agp + k0,                alp);
        gl_lds16(agp + k0 + (size_t)16 * ENC, alp + 16 * 32);
        gl_lds16(bgp + k0,                blp);
        gl_lds16(bgp + k0 + (size_t)16 * ENC, blp + 16 * 32);
        __syncthreads();                       // drains vmcnt (compiler-inserted)
        half8 af[4], bf[4];
        #pragma unroll
        for (int i = 0; i < 4; ++i)
            af[i] = *(const half8*)(&As[(wm + i * 16 + col) * 32 + q * 8]);
        #pragma unroll
        for (int j = 0; j < 4; ++j)
            bf[j] = *(const half8*)(&Bs[(wn + j * 16 + col) * 32 + q * 8]);
        #pragma unroll
        for (int i = 0; i < 4; ++i)
            #pragma unroll
            for (int j = 0; j < 4; ++j)
                acc[i][j] = __builtin_amdgcn_mfma_f32_16x16x32_f16(af[i], bf[j], acc[i][j], 0, 0, 0);
    }

    // epilogue: v = acc + hp; score-row += tanh(v)*Wv, reduced over this block's 128 n
    float hpv[4], wvv[4];
    #pragma unroll
    for (int j = 0; j < 4; ++j) {
        int n = n0 + wn + j * 16 + col;
        hpv[j] = hp[b * 1024 + n];
        wvv[j] = wv[n];
    }
    #pragma unroll
    for (int i = 0; i < 4; ++i) {
        float rs0 = 0.f, rs1 = 0.f, rs2 = 0.f, rs3 = 0.f;
        #pragma unroll
        for (int j = 0; j < 4; ++j) {
            rs0 += fast_tanh(acc[i][j][0] + hpv[j]) * wvv[j];
            rs1 += fast_tanh(acc[i][j][1] + hpv[j]) * wvv[j];
            rs2 += fast_tanh(acc[i][j][2] + hpv[j]) * wvv[j];
            rs3 += fast_tanh(acc[i][j][3] + hpv[j]) * wvv[j];
        }
        #pragma unroll
        for (int off = 1; off < 16; off <<= 1) {
            rs0 += __shfl_xor(rs0, off);
            rs1 += __shfl_xor(rs1, off);
            rs2 += __shfl_xor(rs2, off);
            rs3 += __shfl_xor(rs3, off);
        }
        if (col == 0) {
            const int mrow = m0 + wm + i * 16 + q * 4;
            atomicAdd(&scores[mrow + 0], rs0);
            atomicAdd(&scores[mrow + 1], rs1);
            atomicAdd(&scores[mrow + 2], rs2);
            atomicAdd(&scores[mrow + 3], rs3);
        }
    }
}

// ---- K2 fallback (ws too small for f16 copy): original register-staged kernel ----
__global__ __launch_bounds__(256) void k_score(
    const float* __restrict__ enc, const _Float16* __restrict__ w1t,
    const float* __restrict__ hp, const float* __restrict__ wv,
    float* __restrict__ scores)
{
    __shared__ _Float16 As[128 * 40];
    __shared__ _Float16 Bs[128 * 40];
    const int n0 = blockIdx.x * 128;
    const int m0 = blockIdx.y * 128;
    const int b  = m0 >> 9;
    const int t = threadIdx.x;
    const int lane = t & 63, w = t >> 6;
    const int wm = (w >> 1) * 64, wn = (w & 1) * 64;
    const int col = lane & 15, q = lane >> 4;

    floatx4 acc[4][4];
    #pragma unroll
    for (int i = 0; i < 4; ++i)
        #pragma unroll
        for (int j = 0; j < 4; ++j) acc[i][j] = (floatx4){0.f, 0.f, 0.f, 0.f};

    const int sr = t >> 1;
    const int sc = (t & 1) * 16;
    const float*    ag = enc + (size_t)(m0 + sr) * ENC + sc;
    const _Float16* bg = w1t + (size_t)(n0 + sr) * ENC + sc;
    _Float16* asw = &As[sr * 40 + sc];
    _Float16* bsw = &Bs[sr * 40 + sc];

    for (int k0 = 0; k0 < ENC; k0 += 32) {
        __syncthreads();
        floatx4 a0 = *(const floatx4*)(ag + k0);
        floatx4 a1 = *(const floatx4*)(ag + k0 + 4);
        floatx4 a2 = *(const floatx4*)(ag + k0 + 8);
        floatx4 a3 = *(const floatx4*)(ag + k0 + 12);
        half8 bv0 = *(const half8*)(bg + k0);
        half8 bv1 = *(const half8*)(bg + k0 + 8);
        half8 ha, hb;
        #pragma unroll
        for (int e = 0; e < 4; ++e) { ha[e] = (_Float16)a0[e]; ha[e + 4] = (_Float16)a1[e]; }
        #pragma unroll
        for (int e = 0; e < 4; ++e) { hb[e] = (_Float16)a2[e]; hb[e + 4] = (_Float16)a3[e]; }
        *(half8*)(asw)     = ha;
        *(half8*)(asw + 8) = hb;
        *(half8*)(bsw)     = bv0;
        *(half8*)(bsw + 8) = bv1;
        __syncthreads();
        half8 af[4], bf[4];
        #pragma unroll
        for (int i = 0; i < 4; ++i)
            af[i] = *(const half8*)(&As[(wm + i * 16 + col) * 40 + q * 8]);
        #pragma unroll
        for (int j = 0; j < 4; ++j)
            bf[j] = *(const half8*)(&Bs[(wn + j * 16 + col) * 40 + q * 8]);
        #pragma unroll
        for (int i = 0; i < 4; ++i)
            #pragma unroll
            for (int j = 0; j < 4; ++j)
                acc[i][j] = __builtin_amdgcn_mfma_f32_16x16x32_f16(af[i], bf[j], acc[i][j], 0, 0, 0);
    }

    float hpv[4], wvv[4];
    #pragma unroll
    for (int j = 0; j < 4; ++j) {
        int n = n0 + wn + j * 16 + col;
        hpv[j] = hp[b * 1024 + n];
        wvv[j] = wv[n];
    }
    #pragma unroll
    for (int i = 0; i < 4; ++i) {
        float rs0 = 0.f, rs1 = 0.f, rs2 = 0.f, rs3 = 0.f;
        #pragma unroll
        for (int j = 0; j < 4; ++j) {
            rs0 += fast_tanh(acc[i][j][0] + hpv[j]) * wvv[j];
            rs1 += fast_tanh(acc[i][j][1] + hpv[j]) * wvv[j];
            rs2 += fast_tanh(acc[i][j][2] + hpv[j]) * wvv[j];
            rs3 += fast_tanh(acc[i][j][3] + hpv[j]) * wvv[j];
        }
        #pragma unroll
        for (int off = 1; off < 16; off <<= 1) {
            rs0 += __shfl_xor(rs0, off);
            rs1 += __shfl_xor(rs1, off);
            rs2 += __shfl_xor(rs2, off);
            rs3 += __shfl_xor(rs3, off);
        }
        if (col == 0) {
            const int mrow = m0 + wm + i * 16 + q * 4;
            atomicAdd(&scores[mrow + 0], rs0);
            atomicAdd(&scores[mrow + 1], rs1);
            atomicAdd(&scores[mrow + 2], rs2);
            atomicAdd(&scores[mrow + 3], rs3);
        }
    }
}

// ---- K3: softmax over S per batch row -> aw (d_out); also gather emb into x[:,1024:1280] ----
__global__ void k_softmax_emb(const float* __restrict__ scores, const int* __restrict__ tok,
                              const float* __restrict__ emb, float* __restrict__ aw,
                              float* __restrict__ x) {
    const int b = blockIdx.x, t = threadIdx.x; // 256 threads
    float s0 = scores[b * SS + t];
    float s1 = scores[b * SS + 256 + t];
    float mx = fmaxf(s0, s1);
    for (int off = 32; off; off >>= 1) mx = fmaxf(mx, __shfl_xor(mx, off));
    __shared__ float redm[4], reds[4];
    const int w = t >> 6, lane = t & 63;
    if (lane == 0) redm[w] = mx;
    __syncthreads();
    mx = fmaxf(fmaxf(redm[0], redm[1]), fmaxf(redm[2], redm[3]));
    float e0 = exp2f((s0 - mx) * 1.44269504f);
    float e1 = exp2f((s1 - mx) * 1.44269504f);
    float sm = e0 + e1;
    for (int off = 32; off; off >>= 1) sm += __shfl_xor(sm, off);
    if (lane == 0) reds[w] = sm;
    __syncthreads();
    sm = reds[0] + reds[1] + reds[2] + reds[3];
    const float inv = 1.0f / sm;
    aw[b * SS + t]       = e0 * inv;
    aw[b * SS + 256 + t] = e1 * inv;
    x[(size_t)b * XCOLS + ENC + t] = emb[(size_t)tok[b] * EMB + t];
}

// ---- K4: context[b][e] = sum_s aw[b][s] * enc[b][s][e] -> x[:,0:1024] ----
__global__ void k_context(const float* __restrict__ enc, const float* __restrict__ aw,
                          float* __restrict__ x) {
    const int b = blockIdx.x >> 2;
    const int e = (blockIdx.x & 3) * 256 + threadIdx.x;
    const float* ep = enc + (size_t)b * SS * ENC + e;
    const float* ap = aw + b * SS;
    float acc = 0.f;
    #pragma unroll 8
    for (int s = 0; s < SS; ++s) acc += ap[s] * ep[(size_t)s * ENC];
    x[(size_t)b * XCOLS + e] = acc;
}

// ---- K5: z[b][n] = x[b]@lstm_k[:,n]  (bias added in gates) ----
__global__ void k_lstm(const float* __restrict__ x, const float* __restrict__ lk,
                       float* __restrict__ z) {
    __shared__ float xs[8 * XCOLS]; // 40 KB
    const int t = threadIdx.x;              // 128
    const int n = blockIdx.x * 128 + t;     // 32 n-tiles
    const int b0 = blockIdx.y * 8;          // 16 b-tiles
    for (int i = t; i < 2560; i += 128)
        ((floatx4*)xs)[i] = ((const floatx4*)(x + (size_t)b0 * XCOLS))[i];
    __syncthreads();
    float acc[8] = {0, 0, 0, 0, 0, 0, 0, 0};
    for (int k = 0; k < XCOLS; ++k) {
        float wval = lk[(size_t)k * NG + n];
        #pragma unroll
        for (int j = 0; j < 8; ++j) acc[j] += xs[j * XCOLS + k] * wval;
    }
    #pragma unroll
    for (int j = 0; j < 8; ++j) z[(size_t)(b0 + j) * NG + n] = acc[j];
}

// ---- K6: gates (keras order i,f,g,o; c0=0 so f drops out) ----
__global__ void k_gates(const float* __restrict__ z, const float* __restrict__ lb,
                        float* __restrict__ h_out, float* __restrict__ c_out) {
    const int idx = blockIdx.x * 256 + threadIdx.x; // 131072
    const int b = idx >> 10, d = idx & 1023;
    const float* zb = z + (size_t)b * NG;
    float iv = zb[d]        + lb[d];
    float gv = zb[d + 2048] + lb[d + 2048];
    float ov = zb[d + 3072] + lb[d + 3072];
    float c = fast_sigmoid(iv) * fast_tanh(gv);
    float h = fast_sigmoid(ov) * fast_tanh(c);
    h_out[idx] = h;
    c_out[idx] = c;
}

// ---- K7: logits = h @ fc_W + fc_b  (f16 MFMA, M=128 all batch, BN=128, BK=32) ----
__global__ __launch_bounds__(256) void k_fc(
    const float* __restrict__ hsrc, const float* __restrict__ fcW,
    const float* __restrict__ fcb, float* __restrict__ logits)
{
    __shared__ _Float16 As[128 * 40];
    __shared__ _Float16 Bs[128 * 40];
    const int n0 = blockIdx.x * 128; // 250 blocks
    const int t = threadIdx.x;
    const int lane = t & 63, w = t >> 6;
    const int wm = (w >> 1) * 64, wn = (w & 1) * 64;
    const int col = lane & 15, q = lane >> 4;

    floatx4 acc[4][4];
    #pragma unroll
    for (int i = 0; i < 4; ++i)
        #pragma unroll
        for (int j = 0; j < 4; ++j) acc[i][j] = (floatx4){0.f, 0.f, 0.f, 0.f};

    const int sr = t >> 1, sc = (t & 1) * 16;
    const float* ag = hsrc + (size_t)sr * 1024 + sc;
    _Float16* asw = &As[sr * 40 + sc];
    const int bn = (t & 31) * 4;    // n within tile
    const int bk = (t >> 5) * 4;    // k within BK

    for (int k0 = 0; k0 < 1024; k0 += 32) {
        __syncthreads();
        floatx4 a0 = *(const floatx4*)(ag + k0);
        floatx4 a1 = *(const floatx4*)(ag + k0 + 4);
        floatx4 a2 = *(const floatx4*)(ag + k0 + 8);
        floatx4 a3 = *(const floatx4*)(ag + k0 + 12);
        half8 ha, hb;
        #pragma unroll
        for (int e = 0; e < 4; ++e) { ha[e] = (_Float16)a0[e]; ha[e + 4] = (_Float16)a1[e]; }
        #pragma unroll
        for (int e = 0; e < 4; ++e) { hb[e] = (_Float16)a2[e]; hb[e + 4] = (_Float16)a3[e]; }
        *(half8*)(asw)     = ha;
        *(half8*)(asw + 8) = hb;
        // B: 4k x 4n micro-tile, transpose to [n][k] in LDS
        floatx4 w0 = *(const floatx4*)(fcW + (size_t)(k0 + bk + 0) * VOCAB + n0 + bn);
        floatx4 w1 = *(const floatx4*)(fcW + (size_t)(k0 + bk + 1) * VOCAB + n0 + bn);
        floatx4 w2 = *(const floatx4*)(fcW + (size_t)(k0 + bk + 2) * VOCAB + n0 + bn);
        floatx4 w3 = *(const floatx4*)(fcW + (size_t)(k0 + bk + 3) * VOCAB + n0 + bn);
        #pragma unroll
        for (int c = 0; c < 4; ++c) {
            half4 p = { (_Float16)w0[c], (_Float16)w1[c], (_Float16)w2[c], (_Float16)w3[c] };
            *(half4*)(&Bs[(bn + c) * 40 + bk]) = p;
        }
        __syncthreads();
        half8 af[4], bf[4];
        #pragma unroll
        for (int i = 0; i < 4; ++i)
            af[i] = *(const half8*)(&As[(wm + i * 16 + col) * 40 + q * 8]);
        #pragma unroll
        for (int j = 0; j < 4; ++j)
            bf[j] = *(const half8*)(&Bs[(wn + j * 16 + col) * 40 + q * 8]);
        #pragma unroll
        for (int i = 0; i < 4; ++i)
            #pragma unroll
            for (int j = 0; j < 4; ++j)
                acc[i][j] = __builtin_amdgcn_mfma_f32_16x16x32_f16(af[i], bf[j], acc[i][j], 0, 0, 0);
    }

    float fcbv[4];
    #pragma unroll
    for (int j = 0; j < 4; ++j) fcbv[j] = fcb[n0 + wn + j * 16 + col];
    #pragma unroll
    for (int i = 0; i < 4; ++i)
        #pragma unroll
        for (int j = 0; j < 4; ++j)
            #pragma unroll
            for (int r = 0; r < 4; ++r) {
                const int row = wm + i * 16 + q * 4 + r;
                logits[(size_t)row * VOCAB + n0 + wn + j * 16 + col] = acc[i][j][r] + fcbv[j];
            }
}

extern "C" void kernel_launch(void* const* d_in, const int* in_sizes, int n_in,
                              void* d_out, int out_size, void* d_ws, size_t ws_size,
                              hipStream_t stream) {
    const int*   tok    = (const int*)d_in[0];
    const float* dh     = (const float*)d_in[1];
    const float* enc    = (const float*)d_in[2];
    const float* emb    = (const float*)d_in[3];
    const float* W1     = (const float*)d_in[4];
    const float* b1     = (const float*)d_in[5];
    const float* W2     = (const float*)d_in[6];
    const float* b2     = (const float*)d_in[7];
    const float* Wv     = (const float*)d_in[8];
    // d_in[9] bv: cancels in softmax, unused. d_in[11] lstm_rk: multiplies h0=0, unused.
    const float* lstm_k = (const float*)d_in[10];
    const float* lstm_b = (const float*)d_in[12];
    const float* fc_W   = (const float*)d_in[13];
    const float* fc_b   = (const float*)d_in[14];

    float* out    = (float*)d_out;
    float* logits = out;                                   // 128*32000
    float* h_out  = out + 4096000;                         // 128*1024
    float* c_out  = out + 4096000 + 131072;                // 128*1024
    float* aw     = out + 4096000 + 262144;                // 128*512

    char* ws = (char*)d_ws;
    _Float16* w1t    = (_Float16*)ws;                      // 2 MB
    float*    hp     = (float*)(ws + 2097152);             // 512 KB
    float*    scores = (float*)(ws + 2621440);             // 256 KB
    float*    x      = (float*)(ws + 2883584);             // 640 KB
    float*    z      = (float*)(ws + 3538944);             // 2 MB
    _Float16* ench   = (_Float16*)(ws + 6291456);          // 128 MB (fast path only)

    const size_t need_fast = 6291456 + (size_t)MTOT * ENC * sizeof(_Float16);
    const bool fast = ws_size >= need_fast;

    hipMemsetAsync(scores, 0, MTOT * sizeof(float), stream); // atomicAdd target
    k_transpose_w1<<<dim3(32, 32), dim3(32, 8), 0, stream>>>(W1, w1t);
    k_hidden_proj<<<dim3(8, 16), 128, 0, stream>>>(dh, W2, b1, b2, hp);
    if (fast) {
        k_convert<<<2048, 256, 0, stream>>>(enc, ench);
        // XCD-grouped 1D grid: all 8 n-blocks of an m-tile run back-to-back on one XCD
        k_score_f16<<<4096, 256, 0, stream>>>(ench, w1t, hp, Wv, scores);
    } else {
        k_score<<<dim3(8, 512), 256, 0, stream>>>(enc, w1t, hp, Wv, scores);
    }
    k_softmax_emb<<<128, 256, 0, stream>>>(scores, tok, emb, aw, x);
    k_context<<<512, 256, 0, stream>>>(enc, aw, x);
    k_lstm<<<dim3(32, 16), 128, 0, stream>>>(x, lstm_k, z);
    k_gates<<<512, 256, 0, stream>>>(z, lstm_b, h_out, c_out);
    k_fc<<<250, 256, 0, stream>>>(h_out, fc_W, fc_b, logits);
}

// Round 2
// 888.831 us; speedup vs baseline: 1.1092x; 1.0975x over previous
//
#include <hip/hip_runtime.h>
#include <hip/hip_bf16.h>
#include <stdint.h>

// ---- problem constants ----
#define VOCAB 32000
#define EMB   256
#define DEC   1024
#define ENC   1024
#define BB    128
#define SS    512
#define MTOT  (BB * SS)      // 65536
#define XCOLS (ENC + EMB)    // 1280
#define NG    (4 * DEC)      // 4096

typedef _Float16 half8  __attribute__((ext_vector_type(8)));
typedef _Float16 half4  __attribute__((ext_vector_type(4)));
typedef float    floatx4 __attribute__((ext_vector_type(4)));

__device__ __forceinline__ float fast_tanh(float x) {
    float e = __builtin_amdgcn_exp2f(x * 2.885390082f); // e^(2x)
    return 1.0f - 2.0f * __builtin_amdgcn_rcpf(e + 1.0f);
}
__device__ __forceinline__ float fast_sigmoid(float x) {
    float e = __builtin_amdgcn_exp2f(-x * 1.442695041f); // e^(-x)
    return __builtin_amdgcn_rcpf(1.0f + e);
}

// async global->LDS, 16B per lane. LDS dest is wave-uniform base + lane*16.
__device__ __forceinline__ void gl_lds16(const void* g, void* l) {
    __builtin_amdgcn_global_load_lds(
        (const __attribute__((address_space(1))) uint32_t*)g,
        (__attribute__((address_space(3))) uint32_t*)l,
        16, 0, 0);
}

// ---- K0: W1 (K=ENC, N=DEC) fp32 -> w1t f16 [n][k] ----
__global__ void k_transpose_w1(const float* __restrict__ W1, _Float16* __restrict__ w1t) {
    __shared__ float tile[32][33];
    const int k0 = blockIdx.y * 32, n0 = blockIdx.x * 32;
    const int tx = threadIdx.x, ty = threadIdx.y; // (32,8)
    #pragma unroll
    for (int j = 0; j < 4; ++j)
        tile[ty + j * 8][tx] = W1[(size_t)(k0 + ty + j * 8) * DEC + n0 + tx];
    __syncthreads();
    #pragma unroll
    for (int j = 0; j < 4; ++j)
        w1t[(size_t)(n0 + ty + j * 8) * ENC + k0 + tx] = (_Float16)tile[tx][ty + j * 8];
}

// ---- K0b: enc fp32 -> f16 copy ----
__global__ void k_convert(const float* __restrict__ src, _Float16* __restrict__ dst) {
    const int stride = gridDim.x * blockDim.x;
    const int n8 = (MTOT * ENC) / 8;          // 8388608 half8 stores
    for (int i = blockIdx.x * blockDim.x + threadIdx.x; i < n8; i += stride) {
        floatx4 a = ((const floatx4*)src)[2 * i];
        floatx4 b = ((const floatx4*)src)[2 * i + 1];
        half8 h;
        #pragma unroll
        for (int e = 0; e < 4; ++e) { h[e] = (_Float16)a[e]; h[e + 4] = (_Float16)b[e]; }
        ((half8*)dst)[i] = h;
    }
}

// ---- K1: hp[b][n] += dh[b][k0:k0+128]@W2[k0:,n] (+bias on split 0) ----
// grid (8 n-tiles, 16 b-tiles, 8 k-splits), block 128. hp must be zeroed.
__global__ void k_hidden_proj(const float* __restrict__ dh, const float* __restrict__ W2,
                              const float* __restrict__ b1, const float* __restrict__ b2,
                              float* __restrict__ hp) {
    __shared__ float xs[8 * 128];
    const int t = threadIdx.x;                 // 128
    const int n = blockIdx.x * 128 + t;
    const int b0 = blockIdx.y * 8;
    const int k0 = blockIdx.z * 128;
    for (int i = t; i < 1024; i += 128) {
        const int j = i >> 7, kk = i & 127;
        xs[i] = dh[(size_t)(b0 + j) * 1024 + k0 + kk];
    }
    __syncthreads();
    float acc[8] = {0, 0, 0, 0, 0, 0, 0, 0};
    for (int k = 0; k < 128; ++k) {
        float wval = W2[(size_t)(k0 + k) * 1024 + n];
        #pragma unroll
        for (int j = 0; j < 8; ++j) acc[j] += xs[j * 128 + k] * wval;
    }
    const float bias = (blockIdx.z == 0) ? (b1[n] + b2[n]) : 0.0f;
    #pragma unroll
    for (int j = 0; j < 8; ++j)
        atomicAdd(&hp[(size_t)(b0 + j) * 1024 + n], acc[j] + bias);
}

// ---- K2 fast: score GEMM, f16 MFMA, gl_lds staging, double-buffered prefetch,
//      XCD-grouped block mapping. grid 4096: bits[2:0]=xcd, [5:3]=n, [11:6]=m. ----
__global__ __launch_bounds__(256) void k_score_f16(
    const _Float16* __restrict__ ench, const _Float16* __restrict__ w1t,
    const float* __restrict__ hp, const float* __restrict__ wv,
    float* __restrict__ scores)
{
    __shared__ _Float16 As[2][128 * 32];   // 2 x 8 KB
    __shared__ _Float16 Bs[2][128 * 32];
    const int g   = blockIdx.x;
    const int xcd = g & 7;
    const int n0  = ((g >> 3) & 7) * 128;
    const int m0  = ((xcd << 6) + (g >> 6)) << 7;
    const int b   = m0 >> 9;
    const int t = threadIdx.x;
    const int lane = t & 63, w = t >> 6;
    const int wm = (w >> 1) * 64, wn = (w & 1) * 64;
    const int col = lane & 15, q = lane >> 4;

    floatx4 acc[4][4];
    #pragma unroll
    for (int i = 0; i < 4; ++i)
        #pragma unroll
        for (int j = 0; j < 4; ++j) acc[i][j] = (floatx4){0.f, 0.f, 0.f, 0.f};

    // staging: wave w owns rows [w*32, w*32+32). One gl_lds16 = 1 KB = 16 rows.
    const int srow = w * 32 + (lane >> 2);
    const int scol = (lane & 3) * 8;
    const _Float16* agp = ench + (size_t)(m0 + srow) * ENC + scol;
    const _Float16* bgp = w1t  + (size_t)(n0 + srow) * ENC + scol;
    const int lofs = (w * 32) * 32;

    #define STAGE(buf, kk) do {                         \
        gl_lds16(agp + (kk),              &As[buf][lofs]);           \
        gl_lds16(agp + (kk) + 16 * ENC,   &As[buf][lofs + 16 * 32]); \
        gl_lds16(bgp + (kk),              &Bs[buf][lofs]);           \
        gl_lds16(bgp + (kk) + 16 * ENC,   &Bs[buf][lofs + 16 * 32]); \
    } while (0)

    STAGE(0, 0);
    asm volatile("s_waitcnt vmcnt(0)" ::: "memory");
    __builtin_amdgcn_s_barrier();

    for (int it = 0; it < 32; ++it) {
        const int cur = it & 1;
        if (it < 31) STAGE(cur ^ 1, (it + 1) * 32);   // prefetch next tile
        half8 af[4], bf[4];
        #pragma unroll
        for (int i = 0; i < 4; ++i)
            af[i] = *(const half8*)(&As[cur][(wm + i * 16 + col) * 32 + q * 8]);
        #pragma unroll
        for (int j = 0; j < 4; ++j)
            bf[j] = *(const half8*)(&Bs[cur][(wn + j * 16 + col) * 32 + q * 8]);
        #pragma unroll
        for (int i = 0; i < 4; ++i)
            #pragma unroll
            for (int j = 0; j < 4; ++j)
                acc[i][j] = __builtin_amdgcn_mfma_f32_16x16x32_f16(af[i], bf[j], acc[i][j], 0, 0, 0);
        if (it < 31) {
            asm volatile("s_waitcnt vmcnt(0)" ::: "memory"); // my prefetch stores done
            __builtin_amdgcn_s_barrier();                    // everyone's reads+stores done
        }
    }
    #undef STAGE

    // epilogue: score-row += tanh(acc + hp)*Wv, reduced over this block's 128 n
    float hpv[4], wvv[4];
    #pragma unroll
    for (int j = 0; j < 4; ++j) {
        int n = n0 + wn + j * 16 + col;
        hpv[j] = hp[b * 1024 + n];
        wvv[j] = wv[n];
    }
    #pragma unroll
    for (int i = 0; i < 4; ++i) {
        float rs0 = 0.f, rs1 = 0.f, rs2 = 0.f, rs3 = 0.f;
        #pragma unroll
        for (int j = 0; j < 4; ++j) {
            rs0 += fast_tanh(acc[i][j][0] + hpv[j]) * wvv[j];
            rs1 += fast_tanh(acc[i][j][1] + hpv[j]) * wvv[j];
            rs2 += fast_tanh(acc[i][j][2] + hpv[j]) * wvv[j];
            rs3 += fast_tanh(acc[i][j][3] + hpv[j]) * wvv[j];
        }
        #pragma unroll
        for (int off = 1; off < 16; off <<= 1) {
            rs0 += __shfl_xor(rs0, off);
            rs1 += __shfl_xor(rs1, off);
            rs2 += __shfl_xor(rs2, off);
            rs3 += __shfl_xor(rs3, off);
        }
        if (col == 0) {
            const int mrow = m0 + wm + i * 16 + q * 4;
            atomicAdd(&scores[mrow + 0], rs0);
            atomicAdd(&scores[mrow + 1], rs1);
            atomicAdd(&scores[mrow + 2], rs2);
            atomicAdd(&scores[mrow + 3], rs3);
        }
    }
}

// ---- K2 fallback (ws too small for f16 copy) ----
__global__ __launch_bounds__(256) void k_score(
    const float* __restrict__ enc, const _Float16* __restrict__ w1t,
    const float* __restrict__ hp, const float* __restrict__ wv,
    float* __restrict__ scores)
{
    __shared__ _Float16 As[128 * 40];
    __shared__ _Float16 Bs[128 * 40];
    const int n0 = blockIdx.x * 128;
    const int m0 = blockIdx.y * 128;
    const int b  = m0 >> 9;
    const int t = threadIdx.x;
    const int lane = t & 63, w = t >> 6;
    const int wm = (w >> 1) * 64, wn = (w & 1) * 64;
    const int col = lane & 15, q = lane >> 4;

    floatx4 acc[4][4];
    #pragma unroll
    for (int i = 0; i < 4; ++i)
        #pragma unroll
        for (int j = 0; j < 4; ++j) acc[i][j] = (floatx4){0.f, 0.f, 0.f, 0.f};

    const int sr = t >> 1;
    const int sc = (t & 1) * 16;
    const float*    ag = enc + (size_t)(m0 + sr) * ENC + sc;
    const _Float16* bg = w1t + (size_t)(n0 + sr) * ENC + sc;
    _Float16* asw = &As[sr * 40 + sc];
    _Float16* bsw = &Bs[sr * 40 + sc];

    for (int k0 = 0; k0 < ENC; k0 += 32) {
        __syncthreads();
        floatx4 a0 = *(const floatx4*)(ag + k0);
        floatx4 a1 = *(const floatx4*)(ag + k0 + 4);
        floatx4 a2 = *(const floatx4*)(ag + k0 + 8);
        floatx4 a3 = *(const floatx4*)(ag + k0 + 12);
        half8 bv0 = *(const half8*)(bg + k0);
        half8 bv1 = *(const half8*)(bg + k0 + 8);
        half8 ha, hb;
        #pragma unroll
        for (int e = 0; e < 4; ++e) { ha[e] = (_Float16)a0[e]; ha[e + 4] = (_Float16)a1[e]; }
        #pragma unroll
        for (int e = 0; e < 4; ++e) { hb[e] = (_Float16)a2[e]; hb[e + 4] = (_Float16)a3[e]; }
        *(half8*)(asw)     = ha;
        *(half8*)(asw + 8) = hb;
        *(half8*)(bsw)     = bv0;
        *(half8*)(bsw + 8) = bv1;
        __syncthreads();
        half8 af[4], bf[4];
        #pragma unroll
        for (int i = 0; i < 4; ++i)
            af[i] = *(const half8*)(&As[(wm + i * 16 + col) * 40 + q * 8]);
        #pragma unroll
        for (int j = 0; j < 4; ++j)
            bf[j] = *(const half8*)(&Bs[(wn + j * 16 + col) * 40 + q * 8]);
        #pragma unroll
        for (int i = 0; i < 4; ++i)
            #pragma unroll
            for (int j = 0; j < 4; ++j)
                acc[i][j] = __builtin_amdgcn_mfma_f32_16x16x32_f16(af[i], bf[j], acc[i][j], 0, 0, 0);
    }

    float hpv[4], wvv[4];
    #pragma unroll
    for (int j = 0; j < 4; ++j) {
        int n = n0 + wn + j * 16 + col;
        hpv[j] = hp[b * 1024 + n];
        wvv[j] = wv[n];
    }
    #pragma unroll
    for (int i = 0; i < 4; ++i) {
        float rs0 = 0.f, rs1 = 0.f, rs2 = 0.f, rs3 = 0.f;
        #pragma unroll
        for (int j = 0; j < 4; ++j) {
            rs0 += fast_tanh(acc[i][j][0] + hpv[j]) * wvv[j];
            rs1 += fast_tanh(acc[i][j][1] + hpv[j]) * wvv[j];
            rs2 += fast_tanh(acc[i][j][2] + hpv[j]) * wvv[j];
            rs3 += fast_tanh(acc[i][j][3] + hpv[j]) * wvv[j];
        }
        #pragma unroll
        for (int off = 1; off < 16; off <<= 1) {
            rs0 += __shfl_xor(rs0, off);
            rs1 += __shfl_xor(rs1, off);
            rs2 += __shfl_xor(rs2, off);
            rs3 += __shfl_xor(rs3, off);
        }
        if (col == 0) {
            const int mrow = m0 + wm + i * 16 + q * 4;
            atomicAdd(&scores[mrow + 0], rs0);
            atomicAdd(&scores[mrow + 1], rs1);
            atomicAdd(&scores[mrow + 2], rs2);
            atomicAdd(&scores[mrow + 3], rs3);
        }
    }
}

// ---- K3: softmax over S per batch row -> aw; gather emb into x[:,1024:1280] ----
__global__ void k_softmax_emb(const float* __restrict__ scores, const int* __restrict__ tok,
                              const float* __restrict__ emb, float* __restrict__ aw,
                              float* __restrict__ x) {
    const int b = blockIdx.x, t = threadIdx.x; // 256 threads
    float s0 = scores[b * SS + t];
    float s1 = scores[b * SS + 256 + t];
    float mx = fmaxf(s0, s1);
    for (int off = 32; off; off >>= 1) mx = fmaxf(mx, __shfl_xor(mx, off));
    __shared__ float redm[4], reds[4];
    const int w = t >> 6, lane = t & 63;
    if (lane == 0) redm[w] = mx;
    __syncthreads();
    mx = fmaxf(fmaxf(redm[0], redm[1]), fmaxf(redm[2], redm[3]));
    float e0 = exp2f((s0 - mx) * 1.44269504f);
    float e1 = exp2f((s1 - mx) * 1.44269504f);
    float sm = e0 + e1;
    for (int off = 32; off; off >>= 1) sm += __shfl_xor(sm, off);
    if (lane == 0) reds[w] = sm;
    __syncthreads();
    sm = reds[0] + reds[1] + reds[2] + reds[3];
    const float inv = 1.0f / sm;
    aw[b * SS + t]       = e0 * inv;
    aw[b * SS + 256 + t] = e1 * inv;
    x[(size_t)b * XCOLS + ENC + t] = emb[(size_t)tok[b] * EMB + t];
}

// ---- K4: context[b][e] += sum_{s in split} aw[b][s]*enc[b][s][e] -> x[:,0:1024] ----
// grid (128 b x 4 s-splits), block 256, each thread 4 consecutive e. x pre-zeroed.
__global__ void k_context(const float* __restrict__ enc, const float* __restrict__ aw,
                          float* __restrict__ x) {
    const int b  = blockIdx.x >> 2;
    const int s0 = (blockIdx.x & 3) * 128;
    const int e4 = threadIdx.x;                  // 256 threads * 4 floats = 1024
    const float* ep = enc + ((size_t)b * SS + s0) * ENC;
    const float* ap = aw + b * SS + s0;
    float a0 = 0.f, a1 = 0.f, a2 = 0.f, a3 = 0.f;
    #pragma unroll 4
    for (int s = 0; s < 128; ++s) {
        const float a = ap[s];
        floatx4 v = ((const floatx4*)(ep + (size_t)s * ENC))[e4];
        a0 += a * v[0]; a1 += a * v[1]; a2 += a * v[2]; a3 += a * v[3];
    }
    float* xp = x + (size_t)b * XCOLS + e4 * 4;
    atomicAdd(xp + 0, a0);
    atomicAdd(xp + 1, a1);
    atomicAdd(xp + 2, a2);
    atomicAdd(xp + 3, a3);
}

// ---- K5: z[b][n] += x[b][k0:]@lstm_k[k0:,n] ----
// grid (32 n-tiles, 16 b-tiles, 4 k-splits of 320), block 128. z pre-zeroed.
__global__ void k_lstm(const float* __restrict__ x, const float* __restrict__ lk,
                       float* __restrict__ z) {
    __shared__ float xs[8 * 320]; // 10 KB
    const int t = threadIdx.x;              // 128
    const int n = blockIdx.x * 128 + t;
    const int b0 = blockIdx.y * 8;
    const int k0 = blockIdx.z * 320;
    #pragma unroll
    for (int j = 0; j < 8; ++j)
        for (int kk = t; kk < 320; kk += 128)
            xs[j * 320 + kk] = x[(size_t)(b0 + j) * XCOLS + k0 + kk];
    __syncthreads();
    float acc[8] = {0, 0, 0, 0, 0, 0, 0, 0};
    for (int k = 0; k < 320; ++k) {
        float wval = lk[(size_t)(k0 + k) * NG + n];
        #pragma unroll
        for (int j = 0; j < 8; ++j) acc[j] += xs[j * 320 + k] * wval;
    }
    #pragma unroll
    for (int j = 0; j < 8; ++j)
        atomicAdd(&z[(size_t)(b0 + j) * NG + n], acc[j]);
}

// ---- K6: gates (keras order i,f,g,o; c0=0 so f drops out) ----
__global__ void k_gates(const float* __restrict__ z, const float* __restrict__ lb,
                        float* __restrict__ h_out, float* __restrict__ c_out) {
    const int idx = blockIdx.x * 256 + threadIdx.x; // 131072
    const int b = idx >> 10, d = idx & 1023;
    const float* zb = z + (size_t)b * NG;
    float iv = zb[d]        + lb[d];
    float gv = zb[d + 2048] + lb[d + 2048];
    float ov = zb[d + 3072] + lb[d + 3072];
    float c = fast_sigmoid(iv) * fast_tanh(gv);
    float h = fast_sigmoid(ov) * fast_tanh(c);
    h_out[idx] = h;
    c_out[idx] = c;
}

// ---- K7: logits = h @ fc_W + fc_b  (f16 MFMA, M=128, BN=128, BK=32) ----
__global__ __launch_bounds__(256) void k_fc(
    const float* __restrict__ hsrc, const float* __restrict__ fcW,
    const float* __restrict__ fcb, float* __restrict__ logits)
{
    __shared__ _Float16 As[128 * 40];
    __shared__ _Float16 Bs[128 * 40];
    const int n0 = blockIdx.x * 128; // 250 blocks
    const int t = threadIdx.x;
    const int lane = t & 63, w = t >> 6;
    const int wm = (w >> 1) * 64, wn = (w & 1) * 64;
    const int col = lane & 15, q = lane >> 4;

    floatx4 acc[4][4];
    #pragma unroll
    for (int i = 0; i < 4; ++i)
        #pragma unroll
        for (int j = 0; j < 4; ++j) acc[i][j] = (floatx4){0.f, 0.f, 0.f, 0.f};

    const int sr = t >> 1, sc = (t & 1) * 16;
    const float* ag = hsrc + (size_t)sr * 1024 + sc;
    _Float16* asw = &As[sr * 40 + sc];
    const int bn = (t & 31) * 4;    // n within tile
    const int bk = (t >> 5) * 4;    // k within BK

    for (int k0 = 0; k0 < 1024; k0 += 32) {
        __syncthreads();
        floatx4 a0 = *(const floatx4*)(ag + k0);
        floatx4 a1 = *(const floatx4*)(ag + k0 + 4);
        floatx4 a2 = *(const floatx4*)(ag + k0 + 8);
        floatx4 a3 = *(const floatx4*)(ag + k0 + 12);
        half8 ha, hb;
        #pragma unroll
        for (int e = 0; e < 4; ++e) { ha[e] = (_Float16)a0[e]; ha[e + 4] = (_Float16)a1[e]; }
        #pragma unroll
        for (int e = 0; e < 4; ++e) { hb[e] = (_Float16)a2[e]; hb[e + 4] = (_Float16)a3[e]; }
        *(half8*)(asw)     = ha;
        *(half8*)(asw + 8) = hb;
        floatx4 w0 = *(const floatx4*)(fcW + (size_t)(k0 + bk + 0) * VOCAB + n0 + bn);
        floatx4 w1 = *(const floatx4*)(fcW + (size_t)(k0 + bk + 1) * VOCAB + n0 + bn);
        floatx4 w2 = *(const floatx4*)(fcW + (size_t)(k0 + bk + 2) * VOCAB + n0 + bn);
        floatx4 w3 = *(const floatx4*)(fcW + (size_t)(k0 + bk + 3) * VOCAB + n0 + bn);
        #pragma unroll
        for (int c = 0; c < 4; ++c) {
            half4 p = { (_Float16)w0[c], (_Float16)w1[c], (_Float16)w2[c], (_Float16)w3[c] };
            *(half4*)(&Bs[(bn + c) * 40 + bk]) = p;
        }
        __syncthreads();
        half8 af[4], bf[4];
        #pragma unroll
        for (int i = 0; i < 4; ++i)
            af[i] = *(const half8*)(&As[(wm + i * 16 + col) * 40 + q * 8]);
        #pragma unroll
        for (int j = 0; j < 4; ++j)
            bf[j] = *(const half8*)(&Bs[(wn + j * 16 + col) * 40 + q * 8]);
        #pragma unroll
        for (int i = 0; i < 4; ++i)
            #pragma unroll
            for (int j = 0; j < 4; ++j)
                acc[i][j] = __builtin_amdgcn_mfma_f32_16x16x32_f16(af[i], bf[j], acc[i][j], 0, 0, 0);
    }

    float fcbv[4];
    #pragma unroll
    for (int j = 0; j < 4; ++j) fcbv[j] = fcb[n0 + wn + j * 16 + col];
    #pragma unroll
    for (int i = 0; i < 4; ++i)
        #pragma unroll
        for (int j = 0; j < 4; ++j)
            #pragma unroll
            for (int r = 0; r < 4; ++r) {
                const int row = wm + i * 16 + q * 4 + r;
                logits[(size_t)row * VOCAB + n0 + wn + j * 16 + col] = acc[i][j][r] + fcbv[j];
            }
}

extern "C" void kernel_launch(void* const* d_in, const int* in_sizes, int n_in,
                              void* d_out, int out_size, void* d_ws, size_t ws_size,
                              hipStream_t stream) {
    const int*   tok    = (const int*)d_in[0];
    const float* dh     = (const float*)d_in[1];
    const float* enc    = (const float*)d_in[2];
    const float* emb    = (const float*)d_in[3];
    const float* W1     = (const float*)d_in[4];
    const float* b1     = (const float*)d_in[5];
    const float* W2     = (const float*)d_in[6];
    const float* b2     = (const float*)d_in[7];
    const float* Wv     = (const float*)d_in[8];
    // d_in[9] bv: cancels in softmax. d_in[11] lstm_rk: multiplies h0=0, unused.
    const float* lstm_k = (const float*)d_in[10];
    const float* lstm_b = (const float*)d_in[12];
    const float* fc_W   = (const float*)d_in[13];
    const float* fc_b   = (const float*)d_in[14];

    float* out    = (float*)d_out;
    float* logits = out;                                   // 128*32000
    float* h_out  = out + 4096000;                         // 128*1024
    float* c_out  = out + 4096000 + 131072;                // 128*1024
    float* aw     = out + 4096000 + 262144;                // 128*512

    char* ws = (char*)d_ws;
    _Float16* w1t    = (_Float16*)ws;                      // 2 MB
    float*    hp     = (float*)(ws + 2097152);             // 512 KB
    float*    scores = (float*)(ws + 2621440);             // 256 KB
    float*    x      = (float*)(ws + 2883584);             // 640 KB
    float*    z      = (float*)(ws + 3538944);             // 2 MB
    _Float16* ench   = (_Float16*)(ws + 6291456);          // 128 MB (fast path only)

    const size_t need_fast = 6291456 + (size_t)MTOT * ENC * sizeof(_Float16);
    const bool fast = ws_size >= need_fast;

    // zero all atomic targets up front
    hipMemsetAsync(scores, 0, MTOT * sizeof(float), stream);
    hipMemsetAsync(hp, 0, BB * DEC * sizeof(float), stream);
    hipMemsetAsync(x, 0, (size_t)BB * XCOLS * sizeof(float), stream);
    hipMemsetAsync(z, 0, (size_t)BB * NG * sizeof(float), stream);

    k_transpose_w1<<<dim3(32, 32), dim3(32, 8), 0, stream>>>(W1, w1t);
    k_hidden_proj<<<dim3(8, 16, 8), 128, 0, stream>>>(dh, W2, b1, b2, hp);
    if (fast) {
        k_convert<<<2048, 256, 0, stream>>>(enc, ench);
        k_score_f16<<<4096, 256, 0, stream>>>(ench, w1t, hp, Wv, scores);
    } else {
        k_score<<<dim3(8, 512), 256, 0, stream>>>(enc, w1t, hp, Wv, scores);
    }
    k_softmax_emb<<<128, 256, 0, stream>>>(scores, tok, emb, aw, x);
    k_context<<<512, 256, 0, stream>>>(enc, aw, x);
    k_lstm<<<dim3(32, 16, 4), 128, 0, stream>>>(x, lstm_k, z);
    k_gates<<<512, 256, 0, stream>>>(z, lstm_b, h_out, c_out);
    k_fc<<<250, 256, 0, stream>>>(h_out, fc_W, fc_b, logits);
}

// Round 4
// 848.475 us; speedup vs baseline: 1.1619x; 1.0476x over previous
//
#include <hip/hip_runtime.h>
#include <hip/hip_bf16.h>
#include <stdint.h>

// ---- problem constants ----
#define VOCAB 32000
#define EMB   256
#define DEC   1024
#define ENC   1024
#define BB    128
#define SS    512
#define MTOT  (BB * SS)      // 65536
#define XCOLS (ENC + EMB)    // 1280
#define NG    (4 * DEC)      // 4096
#define BD    (BB * DEC)     // 131072 floats, one hp/ctx slab

typedef _Float16 half8  __attribute__((ext_vector_type(8)));
typedef _Float16 half4  __attribute__((ext_vector_type(4)));
typedef float    floatx4 __attribute__((ext_vector_type(4)));

__device__ __forceinline__ float fast_tanh(float x) {
    float e = __builtin_amdgcn_exp2f(x * 2.885390082f); // e^(2x)
    return 1.0f - 2.0f * __builtin_amdgcn_rcpf(e + 1.0f);
}
__device__ __forceinline__ float fast_sigmoid(float x) {
    float e = __builtin_amdgcn_exp2f(-x * 1.442695041f); // e^(-x)
    return __builtin_amdgcn_rcpf(1.0f + e);
}

// async global->LDS, 16B per lane. LDS dest is wave-uniform base + lane*16.
__device__ __forceinline__ void gl_lds16(const void* g, void* l) {
    __builtin_amdgcn_global_load_lds(
        (const __attribute__((address_space(1))) uint32_t*)g,
        (__attribute__((address_space(3))) uint32_t*)l,
        16, 0, 0);
}

// ---- K_prep: fused {enc->f16 convert | W1 transpose->f16 | hidden_proj k-split} ----
// blocks [0,2048): convert (skipped if !do_convert); [2048,3072): transpose;
// [3072,3328): hidden_proj. hp4: 4 k-split slabs [kz][b][n], slab 0 carries bias.
__global__ __launch_bounds__(256) void k_prep(
    const float* __restrict__ enc, _Float16* __restrict__ ench,
    const float* __restrict__ W1, _Float16* __restrict__ w1t,
    const float* __restrict__ dh, const float* __restrict__ W2,
    const float* __restrict__ b1, const float* __restrict__ b2,
    float* __restrict__ hp4, int do_convert)
{
    __shared__ float tile[32][33];   // transpose branch
    __shared__ float xs[8 * 256];    // hidden_proj branch
    const int bid = blockIdx.x, t = threadIdx.x;

    if (bid < 2048) {
        if (!do_convert) return;
        // enc fp32 -> f16, 2048 blocks x 16 iters x 256 thr x half8
        const int base = bid * 4096 + t;
        #pragma unroll
        for (int it = 0; it < 16; ++it) {
            const int i = base + it * 256;      // half8 index, < 8388608
            floatx4 a = ((const floatx4*)enc)[2 * i];
            floatx4 c = ((const floatx4*)enc)[2 * i + 1];
            half8 h;
            #pragma unroll
            for (int e = 0; e < 4; ++e) { h[e] = (_Float16)a[e]; h[e + 4] = (_Float16)c[e]; }
            ((half8*)ench)[i] = h;
        }
    } else if (bid < 3072) {
        // W1 (K=ENC, N=DEC) fp32 -> w1t f16 [n][k]
        const int p = bid - 2048;
        const int n0 = (p & 31) * 32, k0 = (p >> 5) * 32;
        const int tx = t & 31, ty = t >> 5;     // (32,8)
        #pragma unroll
        for (int j = 0; j < 4; ++j)
            tile[ty + j * 8][tx] = W1[(size_t)(k0 + ty + j * 8) * DEC + n0 + tx];
        __syncthreads();
        #pragma unroll
        for (int j = 0; j < 4; ++j)
            w1t[(size_t)(n0 + ty + j * 8) * ENC + k0 + tx] = (_Float16)tile[tx][ty + j * 8];
    } else {
        // hp4[kz][b][n] = dh[b][k0:k0+256] @ W2[k0:,n] (+bias on kz==0)
        const int p  = bid - 3072;              // 0..255
        const int n  = (p & 3) * 256 + t;
        const int b0 = ((p >> 2) & 15) * 8;
        const int kz = p >> 6;                  // 0..3
        const int k0 = kz * 256;
        for (int i = t; i < 2048; i += 256) {
            const int j = i >> 8, kk = i & 255;
            xs[i] = dh[(size_t)(b0 + j) * 1024 + k0 + kk];
        }
        __syncthreads();
        float acc[8] = {0, 0, 0, 0, 0, 0, 0, 0};
        for (int k = 0; k < 256; ++k) {
            const float wval = W2[(size_t)(k0 + k) * 1024 + n];
            #pragma unroll
            for (int j = 0; j < 8; ++j) acc[j] += xs[j * 256 + k] * wval;
        }
        const float bias = (kz == 0) ? (b1[n] + b2[n]) : 0.0f;
        #pragma unroll
        for (int j = 0; j < 8; ++j)
            hp4[(size_t)kz * BD + (size_t)(b0 + j) * 1024 + n] = acc[j] + bias;
    }
}

// ---- K2 fast: score GEMM, f16 MFMA, gl_lds staging (2-barrier m97 structure),
//      XCD-grouped mapping. grid 4096: bits[2:0]=xcd, [5:3]=n, [11:6]=m.
//      Per-n-block slab scores8[nblk][m]; the two wn-wave-halves are combined
//      through LDS (deterministic; fixes the round-3 store race). ----
__global__ __launch_bounds__(256) void k_score_f16(
    const _Float16* __restrict__ ench, const _Float16* __restrict__ w1t,
    const float* __restrict__ hp4, const float* __restrict__ wv,
    float* __restrict__ scores8)
{
    __shared__ _Float16 As[128 * 32];   // 8 KB, linear [row][k]
    __shared__ _Float16 Bs[128 * 32];
    __shared__ float red[2][128];       // 1 KB cross-wave epilogue scratch
    const int g    = blockIdx.x;
    const int xcd  = g & 7;
    const int nblk = (g >> 3) & 7;
    const int n0   = nblk * 128;
    const int m0   = ((xcd << 6) + (g >> 6)) << 7;
    const int b    = m0 >> 9;
    const int t = threadIdx.x;
    const int lane = t & 63, w = t >> 6;
    const int wm = (w >> 1) * 64, wn = (w & 1) * 64;
    const int col = lane & 15, q = lane >> 4;

    floatx4 acc[4][4];
    #pragma unroll
    for (int i = 0; i < 4; ++i)
        #pragma unroll
        for (int j = 0; j < 4; ++j) acc[i][j] = (floatx4){0.f, 0.f, 0.f, 0.f};

    // staging: wave w owns rows [w*32, w*32+32). One gl_lds16 = 1 KB = 16 rows.
    const int srow = w * 32 + (lane >> 2);
    const int scol = (lane & 3) * 8;
    const _Float16* agp = ench + (size_t)(m0 + srow) * ENC + scol;
    const _Float16* bgp = w1t  + (size_t)(n0 + srow) * ENC + scol;
    _Float16* alp = &As[(w * 32) * 32];
    _Float16* blp = &Bs[(w * 32) * 32];

    for (int k0 = 0; k0 < ENC; k0 += 32) {
        __syncthreads();                       // prev-iter reads done before overwrite
        gl_lds16(agp + k0,                    alp);
        gl_lds16(agp + k0 + (size_t)16 * ENC, alp + 16 * 32);
        gl_lds16(bgp + k0,                    blp);
        gl_lds16(bgp + k0 + (size_t)16 * ENC, blp + 16 * 32);
        __syncthreads();                       // compiler drains vmcnt before barrier
        half8 af[4], bf[4];
        #pragma unroll
        for (int i = 0; i < 4; ++i)
            af[i] = *(const half8*)(&As[(wm + i * 16 + col) * 32 + q * 8]);
        #pragma unroll
        for (int j = 0; j < 4; ++j)
            bf[j] = *(const half8*)(&Bs[(wn + j * 16 + col) * 32 + q * 8]);
        #pragma unroll
        for (int i = 0; i < 4; ++i)
            #pragma unroll
            for (int j = 0; j < 4; ++j)
                acc[i][j] = __builtin_amdgcn_mfma_f32_16x16x32_f16(af[i], bf[j], acc[i][j], 0, 0, 0);
    }

    // epilogue: per-wave partial (64 n) -> red[w&1][row]; combine the two wn halves.
    float hpv[4], wvv[4];
    #pragma unroll
    for (int j = 0; j < 4; ++j) {
        const int n = n0 + wn + j * 16 + col;
        const size_t base = (size_t)b * 1024 + n;
        hpv[j] = hp4[base] + hp4[BD + base] + hp4[2 * BD + base] + hp4[3 * BD + base];
        wvv[j] = wv[n];
    }
    #pragma unroll
    for (int i = 0; i < 4; ++i) {
        float rs0 = 0.f, rs1 = 0.f, rs2 = 0.f, rs3 = 0.f;
        #pragma unroll
        for (int j = 0; j < 4; ++j) {
            rs0 += fast_tanh(acc[i][j][0] + hpv[j]) * wvv[j];
            rs1 += fast_tanh(acc[i][j][1] + hpv[j]) * wvv[j];
            rs2 += fast_tanh(acc[i][j][2] + hpv[j]) * wvv[j];
            rs3 += fast_tanh(acc[i][j][3] + hpv[j]) * wvv[j];
        }
        #pragma unroll
        for (int off = 1; off < 16; off <<= 1) {
            rs0 += __shfl_xor(rs0, off);
            rs1 += __shfl_xor(rs1, off);
            rs2 += __shfl_xor(rs2, off);
            rs3 += __shfl_xor(rs3, off);
        }
        if (col == 0) {
            const int r = wm + i * 16 + q * 4;   // waves 0/2 -> red[0], 1/3 -> red[1]
            red[w & 1][r + 0] = rs0;
            red[w & 1][r + 1] = rs1;
            red[w & 1][r + 2] = rs2;
            red[w & 1][r + 3] = rs3;
        }
    }
    __syncthreads();
    if (t < 128)
        scores8[(size_t)nblk * MTOT + m0 + t] = red[0][t] + red[1][t];
}

// ---- K2 fallback (ws too small for f16 copy): f32 A, atomics into slab 0 ----
__global__ __launch_bounds__(256) void k_score(
    const float* __restrict__ enc, const _Float16* __restrict__ w1t,
    const float* __restrict__ hp4, const float* __restrict__ wv,
    float* __restrict__ scores8)
{
    __shared__ _Float16 As[128 * 40];
    __shared__ _Float16 Bs[128 * 40];
    const int n0 = blockIdx.x * 128;
    const int m0 = blockIdx.y * 128;
    const int b  = m0 >> 9;
    const int t = threadIdx.x;
    const int lane = t & 63, w = t >> 6;
    const int wm = (w >> 1) * 64, wn = (w & 1) * 64;
    const int col = lane & 15, q = lane >> 4;

    floatx4 acc[4][4];
    #pragma unroll
    for (int i = 0; i < 4; ++i)
        #pragma unroll
        for (int j = 0; j < 4; ++j) acc[i][j] = (floatx4){0.f, 0.f, 0.f, 0.f};

    const int sr = t >> 1;
    const int sc = (t & 1) * 16;
    const float*    ag = enc + (size_t)(m0 + sr) * ENC + sc;
    const _Float16* bg = w1t + (size_t)(n0 + sr) * ENC + sc;
    _Float16* asw = &As[sr * 40 + sc];
    _Float16* bsw = &Bs[sr * 40 + sc];

    for (int k0 = 0; k0 < ENC; k0 += 32) {
        __syncthreads();
        floatx4 a0 = *(const floatx4*)(ag + k0);
        floatx4 a1 = *(const floatx4*)(ag + k0 + 4);
        floatx4 a2 = *(const floatx4*)(ag + k0 + 8);
        floatx4 a3 = *(const floatx4*)(ag + k0 + 12);
        half8 bv0 = *(const half8*)(bg + k0);
        half8 bv1 = *(const half8*)(bg + k0 + 8);
        half8 ha, hb;
        #pragma unroll
        for (int e = 0; e < 4; ++e) { ha[e] = (_Float16)a0[e]; ha[e + 4] = (_Float16)a1[e]; }
        #pragma unroll
        for (int e = 0; e < 4; ++e) { hb[e] = (_Float16)a2[e]; hb[e + 4] = (_Float16)a3[e]; }
        *(half8*)(asw)     = ha;
        *(half8*)(asw + 8) = hb;
        *(half8*)(bsw)     = bv0;
        *(half8*)(bsw + 8) = bv1;
        __syncthreads();
        half8 af[4], bf[4];
        #pragma unroll
        for (int i = 0; i < 4; ++i)
            af[i] = *(const half8*)(&As[(wm + i * 16 + col) * 40 + q * 8]);
        #pragma unroll
        for (int j = 0; j < 4; ++j)
            bf[j] = *(const half8*)(&Bs[(wn + j * 16 + col) * 40 + q * 8]);
        #pragma unroll
        for (int i = 0; i < 4; ++i)
            #pragma unroll
            for (int j = 0; j < 4; ++j)
                acc[i][j] = __builtin_amdgcn_mfma_f32_16x16x32_f16(af[i], bf[j], acc[i][j], 0, 0, 0);
    }

    float hpv[4], wvv[4];
    #pragma unroll
    for (int j = 0; j < 4; ++j) {
        const int n = n0 + wn + j * 16 + col;
        const size_t base = (size_t)b * 1024 + n;
        hpv[j] = hp4[base] + hp4[BD + base] + hp4[2 * BD + base] + hp4[3 * BD + base];
        wvv[j] = wv[n];
    }
    #pragma unroll
    for (int i = 0; i < 4; ++i) {
        float rs0 = 0.f, rs1 = 0.f, rs2 = 0.f, rs3 = 0.f;
        #pragma unroll
        for (int j = 0; j < 4; ++j) {
            rs0 += fast_tanh(acc[i][j][0] + hpv[j]) * wvv[j];
            rs1 += fast_tanh(acc[i][j][1] + hpv[j]) * wvv[j];
            rs2 += fast_tanh(acc[i][j][2] + hpv[j]) * wvv[j];
            rs3 += fast_tanh(acc[i][j][3] + hpv[j]) * wvv[j];
        }
        #pragma unroll
        for (int off = 1; off < 16; off <<= 1) {
            rs0 += __shfl_xor(rs0, off);
            rs1 += __shfl_xor(rs1, off);
            rs2 += __shfl_xor(rs2, off);
            rs3 += __shfl_xor(rs3, off);
        }
        if (col == 0) {
            const int mrow = m0 + wm + i * 16 + q * 4;
            atomicAdd(&scores8[mrow + 0], rs0);   // slab 0; slabs 1-7 zeroed by memset
            atomicAdd(&scores8[mrow + 1], rs1);
            atomicAdd(&scores8[mrow + 2], rs2);
            atomicAdd(&scores8[mrow + 3], rs3);
        }
    }
}

// ---- K3: softmax over S per batch row (sums 8 score slabs) -> aw (d_out) ----
__global__ void k_softmax(const float* __restrict__ scores8, float* __restrict__ aw) {
    const int b = blockIdx.x, t = threadIdx.x; // 256 threads
    float s0 = 0.f, s1 = 0.f;
    #pragma unroll
    for (int nb = 0; nb < 8; ++nb) {
        s0 += scores8[(size_t)nb * MTOT + b * SS + t];
        s1 += scores8[(size_t)nb * MTOT + b * SS + 256 + t];
    }
    float mx = fmaxf(s0, s1);
    for (int off = 32; off; off >>= 1) mx = fmaxf(mx, __shfl_xor(mx, off));
    __shared__ float redm[4], reds[4];
    const int w = t >> 6, lane = t & 63;
    if (lane == 0) redm[w] = mx;
    __syncthreads();
    mx = fmaxf(fmaxf(redm[0], redm[1]), fmaxf(redm[2], redm[3]));
    float e0 = exp2f((s0 - mx) * 1.44269504f);
    float e1 = exp2f((s1 - mx) * 1.44269504f);
    float sm = e0 + e1;
    for (int off = 32; off; off >>= 1) sm += __shfl_xor(sm, off);
    if (lane == 0) reds[w] = sm;
    __syncthreads();
    sm = reds[0] + reds[1] + reds[2] + reds[3];
    const float inv = 1.0f / sm;
    aw[b * SS + t]       = e0 * inv;
    aw[b * SS + 256 + t] = e1 * inv;
}

// ---- K4 fast: context from f16 enc (L3-resident), 2 s-split slabs, no atomics ----
__global__ void k_context_f16(const _Float16* __restrict__ ench, const float* __restrict__ aw,
                              float* __restrict__ ctx2) {
    const int b  = blockIdx.x >> 1;
    const int sz = blockIdx.x & 1;
    const int s0 = sz * 256;
    const int e4 = threadIdx.x;                  // 256 thr * 4 floats = 1024
    const _Float16* ep = ench + ((size_t)b * SS + s0) * ENC + e4 * 4;
    const float* ap = aw + b * SS + s0;
    float a0 = 0.f, a1 = 0.f, a2 = 0.f, a3 = 0.f;
    #pragma unroll 8
    for (int s = 0; s < 256; ++s) {
        const float a = ap[s];
        half4 v = *(const half4*)(ep + (size_t)s * ENC);
        a0 += a * (float)v[0]; a1 += a * (float)v[1];
        a2 += a * (float)v[2]; a3 += a * (float)v[3];
    }
    floatx4 r = {a0, a1, a2, a3};
    *(floatx4*)(ctx2 + (size_t)sz * BD + (size_t)b * 1024 + e4 * 4) = r;
}

// ---- K4 fallback: context from f32 enc ----
__global__ void k_context_f32(const float* __restrict__ enc, const float* __restrict__ aw,
                              float* __restrict__ ctx2) {
    const int b  = blockIdx.x >> 1;
    const int sz = blockIdx.x & 1;
    const int s0 = sz * 256;
    const int e4 = threadIdx.x;
    const float* ep = enc + ((size_t)b * SS + s0) * ENC + e4 * 4;
    const float* ap = aw + b * SS + s0;
    float a0 = 0.f, a1 = 0.f, a2 = 0.f, a3 = 0.f;
    #pragma unroll 4
    for (int s = 0; s < 256; ++s) {
        const float a = ap[s];
        floatx4 v = *(const floatx4*)(ep + (size_t)s * ENC);
        a0 += a * v[0]; a1 += a * v[1]; a2 += a * v[2]; a3 += a * v[3];
    }
    floatx4 r = {a0, a1, a2, a3};
    *(floatx4*)(ctx2 + (size_t)sz * BD + (size_t)b * 1024 + e4 * 4) = r;
}

// ---- K5: z2[kz][b][n] = x[b][k0:k0+640]@lstm_k[k0:,n]; x assembled from ctx2+emb ----
// grid (16 n-tiles, 16 b-tiles, 2 k-splits), 256 thr. No atomics.
__global__ void k_lstm(const float* __restrict__ ctx2, const float* __restrict__ emb,
                       const int* __restrict__ tok, const float* __restrict__ lk,
                       float* __restrict__ z2) {
    __shared__ float xs[8 * 640]; // 20 KB
    const int t = threadIdx.x;              // 256
    const int n = blockIdx.x * 256 + t;
    const int b0 = blockIdx.y * 8;
    const int kz = blockIdx.z;
    const int k0 = kz * 640;
    #pragma unroll
    for (int j = 0; j < 8; ++j) {
        const int bb = b0 + j;
        const int tk = tok[bb];
        for (int kk = t; kk < 640; kk += 256) {
            const int gk = k0 + kk;
            float v;
            if (gk < 1024)
                v = ctx2[(size_t)bb * 1024 + gk] + ctx2[(size_t)BD + (size_t)bb * 1024 + gk];
            else
                v = emb[(size_t)tk * EMB + gk - 1024];
            xs[j * 640 + kk] = v;
        }
    }
    __syncthreads();
    float acc[8] = {0, 0, 0, 0, 0, 0, 0, 0};
    #pragma unroll 4
    for (int k = 0; k < 640; ++k) {
        const float wval = lk[(size_t)(k0 + k) * NG + n];
        #pragma unroll
        for (int j = 0; j < 8; ++j) acc[j] += xs[j * 640 + k] * wval;
    }
    #pragma unroll
    for (int j = 0; j < 8; ++j)
        z2[(size_t)kz * BB * NG + (size_t)(b0 + j) * NG + n] = acc[j];
}

// ---- K6: gates (keras i,f,g,o; c0=0 so f drops out). Sums 2 z slabs. ----
__global__ void k_gates(const float* __restrict__ z2, const float* __restrict__ lb,
                        float* __restrict__ h_out, float* __restrict__ c_out) {
    const int idx = blockIdx.x * 256 + threadIdx.x; // 131072
    const int b = idx >> 10, d = idx & 1023;
    const float* z0 = z2 + (size_t)b * NG;
    const float* z1 = z2 + (size_t)BB * NG + (size_t)b * NG;
    float iv = z0[d]        + z1[d]        + lb[d];
    float gv = z0[d + 2048] + z1[d + 2048] + lb[d + 2048];
    float ov = z0[d + 3072] + z1[d + 3072] + lb[d + 3072];
    float c = fast_sigmoid(iv) * fast_tanh(gv);
    float h = fast_sigmoid(ov) * fast_tanh(c);
    h_out[idx] = h;
    c_out[idx] = c;
}

// ---- K7: logits = h @ fc_W + fc_b  (f16 MFMA, M=128, BN=128, BK=32) ----
__global__ __launch_bounds__(256) void k_fc(
    const float* __restrict__ hsrc, const float* __restrict__ fcW,
    const float* __restrict__ fcb, float* __restrict__ logits)
{
    __shared__ _Float16 As[128 * 40];
    __shared__ _Float16 Bs[128 * 40];
    const int n0 = blockIdx.x * 128; // 250 blocks
    const int t = threadIdx.x;
    const int lane = t & 63, w = t >> 6;
    const int wm = (w >> 1) * 64, wn = (w & 1) * 64;
    const int col = lane & 15, q = lane >> 4;

    floatx4 acc[4][4];
    #pragma unroll
    for (int i = 0; i < 4; ++i)
        #pragma unroll
        for (int j = 0; j < 4; ++j) acc[i][j] = (floatx4){0.f, 0.f, 0.f, 0.f};

    const int sr = t >> 1, sc = (t & 1) * 16;
    const float* ag = hsrc + (size_t)sr * 1024 + sc;
    _Float16* asw = &As[sr * 40 + sc];
    const int bn = (t & 31) * 4;    // n within tile
    const int bk = (t >> 5) * 4;    // k within BK

    for (int k0 = 0; k0 < 1024; k0 += 32) {
        __syncthreads();
        floatx4 a0 = *(const floatx4*)(ag + k0);
        floatx4 a1 = *(const floatx4*)(ag + k0 + 4);
        floatx4 a2 = *(const floatx4*)(ag + k0 + 8);
        floatx4 a3 = *(const floatx4*)(ag + k0 + 12);
        half8 ha, hb;
        #pragma unroll
        for (int e = 0; e < 4; ++e) { ha[e] = (_Float16)a0[e]; ha[e + 4] = (_Float16)a1[e]; }
        #pragma unroll
        for (int e = 0; e < 4; ++e) { hb[e] = (_Float16)a2[e]; hb[e + 4] = (_Float16)a3[e]; }
        *(half8*)(asw)     = ha;
        *(half8*)(asw + 8) = hb;
        floatx4 w0 = *(const floatx4*)(fcW + (size_t)(k0 + bk + 0) * VOCAB + n0 + bn);
        floatx4 w1 = *(const floatx4*)(fcW + (size_t)(k0 + bk + 1) * VOCAB + n0 + bn);
        floatx4 w2 = *(const floatx4*)(fcW + (size_t)(k0 + bk + 2) * VOCAB + n0 + bn);
        floatx4 w3 = *(const floatx4*)(fcW + (size_t)(k0 + bk + 3) * VOCAB + n0 + bn);
        #pragma unroll
        for (int c = 0; c < 4; ++c) {
            half4 p = { (_Float16)w0[c], (_Float16)w1[c], (_Float16)w2[c], (_Float16)w3[c] };
            *(half4*)(&Bs[(bn + c) * 40 + bk]) = p;
        }
        __syncthreads();
        half8 af[4], bf[4];
        #pragma unroll
        for (int i = 0; i < 4; ++i)
            af[i] = *(const half8*)(&As[(wm + i * 16 + col) * 40 + q * 8]);
        #pragma unroll
        for (int j = 0; j < 4; ++j)
            bf[j] = *(const half8*)(&Bs[(wn + j * 16 + col) * 40 + q * 8]);
        #pragma unroll
        for (int i = 0; i < 4; ++i)
            #pragma unroll
            for (int j = 0; j < 4; ++j)
                acc[i][j] = __builtin_amdgcn_mfma_f32_16x16x32_f16(af[i], bf[j], acc[i][j], 0, 0, 0);
    }

    float fcbv[4];
    #pragma unroll
    for (int j = 0; j < 4; ++j) fcbv[j] = fcb[n0 + wn + j * 16 + col];
    #pragma unroll
    for (int i = 0; i < 4; ++i)
        #pragma unroll
        for (int j = 0; j < 4; ++j)
            #pragma unroll
            for (int r = 0; r < 4; ++r) {
                const int row = wm + i * 16 + q * 4 + r;
                logits[(size_t)row * VOCAB + n0 + wn + j * 16 + col] = acc[i][j][r] + fcbv[j];
            }
}

extern "C" void kernel_launch(void* const* d_in, const int* in_sizes, int n_in,
                              void* d_out, int out_size, void* d_ws, size_t ws_size,
                              hipStream_t stream) {
    const int*   tok    = (const int*)d_in[0];
    const float* dh     = (const float*)d_in[1];
    const float* enc    = (const float*)d_in[2];
    const float* emb    = (const float*)d_in[3];
    const float* W1     = (const float*)d_in[4];
    const float* b1     = (const float*)d_in[5];
    const float* W2     = (const float*)d_in[6];
    const float* b2     = (const float*)d_in[7];
    const float* Wv     = (const float*)d_in[8];
    // d_in[9] bv: cancels in softmax. d_in[11] lstm_rk: multiplies h0=0, unused.
    const float* lstm_k = (const float*)d_in[10];
    const float* lstm_b = (const float*)d_in[12];
    const float* fc_W   = (const float*)d_in[13];
    const float* fc_b   = (const float*)d_in[14];

    float* out    = (float*)d_out;
    float* logits = out;                                   // 128*32000
    float* h_out  = out + 4096000;                         // 128*1024
    float* c_out  = out + 4096000 + 131072;                // 128*1024
    float* aw     = out + 4096000 + 262144;                // 128*512

    // Workspace layout (lifetimes strictly disjoint on the serial stream):
    //   [0,2M)   w1t      (prep -> score)      | z2 aliases [0,4M) (lstm -> gates)
    //   [2M,4M)  hp4      (prep -> score)      |
    //   [4M,6M)  scores8  (score -> softmax)   | ctx2 aliases [4M,5M) (context -> lstm)
    //   [6M, +128M) ench  (prep -> score, context)
    char* ws = (char*)d_ws;
    _Float16* w1t     = (_Float16*)ws;
    float*    hp4     = (float*)(ws + (2u << 20));
    float*    scores8 = (float*)(ws + (4u << 20));
    float*    ctx2    = (float*)(ws + (4u << 20));
    float*    z2      = (float*)ws;
    _Float16* ench    = (_Float16*)(ws + (6u << 20));

    const size_t need_fast = (6u << 20) + (size_t)MTOT * ENC * sizeof(_Float16);
    const bool fast = ws_size >= need_fast;

    if (fast) {
        k_prep<<<3328, 256, 0, stream>>>(enc, ench, W1, w1t, dh, W2, b1, b2, hp4, 1);
        k_score_f16<<<4096, 256, 0, stream>>>(ench, w1t, hp4, Wv, scores8);
        k_softmax<<<128, 256, 0, stream>>>(scores8, aw);
        k_context_f16<<<256, 256, 0, stream>>>(ench, aw, ctx2);
    } else {
        k_prep<<<3328, 256, 0, stream>>>(enc, ench, W1, w1t, dh, W2, b1, b2, hp4, 0);
        hipMemsetAsync(scores8, 0, 8 * MTOT * sizeof(float), stream);
        k_score<<<dim3(8, 512), 256, 0, stream>>>(enc, w1t, hp4, Wv, scores8);
        k_softmax<<<128, 256, 0, stream>>>(scores8, aw);
        k_context_f32<<<256, 256, 0, stream>>>(enc, aw, ctx2);
    }
    k_lstm<<<dim3(16, 16, 2), 256, 0, stream>>>(ctx2, emb, tok, lstm_k, z2);
    k_gates<<<512, 256, 0, stream>>>(z2, lstm_b, h_out, c_out);
    k_fc<<<250, 256, 0, stream>>>(h_out, fc_W, fc_b, logits);
}